// Round 9
// baseline (20564.149 us; speedup 1.0000x reference)
//
#include <hip/hip_runtime.h>

#define BATCH  64
#define TT     512
#define IDIM   64
#define HDIM   512
#define NAHEAD 24
#define HB     (HDIM * BATCH)

__device__ __forceinline__ float4 ld4(const float* p) {
  return *reinterpret_cast<const float4*>(p);
}
__device__ __forceinline__ float sigm(float x) { return 1.0f / (1.0f + expf(-x)); }

// agent-scope relaxed (sc-bypass) accessors — coherence point = L3, no fences
__device__ __forceinline__ unsigned ldau(const unsigned* p) {
  return __hip_atomic_load(p, __ATOMIC_RELAXED, __HIP_MEMORY_SCOPE_AGENT);
}
__device__ __forceinline__ double lda8(const double* p) {
  return __hip_atomic_load(p, __ATOMIC_RELAXED, __HIP_MEMORY_SCOPE_AGENT);
}
__device__ __forceinline__ void sta(float* p, float v) {
  __hip_atomic_store(p, v, __ATOMIC_RELAXED, __HIP_MEMORY_SCOPE_AGENT);
}
__device__ __forceinline__ void stab(unsigned char* p, unsigned char v) {
  __hip_atomic_store(p, v, __ATOMIC_RELAXED, __HIP_MEMORY_SCOPE_AGENT);
}
// all 4 bytes of v satisfy wrap-safe (int8)(byte - tgt) >= 0
__device__ __forceinline__ int bytes_ge(unsigned v, unsigned tgt) {
  int ok = 1;
#pragma unroll
  for (int i = 0; i < 4; ++i) {
    int d = (int)((v >> (8 * i)) & 0xFF) - (int)tgt;
    ok &= (((d << 24) >> 24) >= 0);
  }
  return ok;
}

// ---------------------------------------------------------------------------
// Persistent 2-layer LSTM encoder. 512 blocks x 512 threads.
// bid = g*64 + wgl: group g (batch rows g*8..g*8+7) x 64 WGs. bid%8 == wgl%8
// -> same-wgl blocks (which read the SAME weight rows) co-locate per XCD:
// per-XCD weight set ~1.6MB stays L2-resident for all 512 steps.
// Pipeline per step t: L0@t (t<512) and L1@(t-1) (t>=1); ONE group barrier
// (64 byte-flags in one 64B line) per step. Group h state ping-pongs in
// [2][8][8][512] agent-scope buffers; each WG stages its group's h into LDS
// (coalesced 8B sc loads) before the dot phase. c-state lives in registers.
// Thread roles: dots: (b=tid&7, d=(tid>>3)&31, layer=tid>>8) — one full-K dot
// per thread; cell: tid<128 (layer=tid>>6, j=(tid>>3)&7, b=tid&7).
// ---------------------------------------------------------------------------
__global__ __launch_bounds__(512, 4)
void lstm_enc(const float* __restrict__ xT,    // [T][I][B]
              const float* __restrict__ wih0, const float* __restrict__ whh0,
              const float* __restrict__ bih0, const float* __restrict__ bhh0,
              const float* __restrict__ wih1, const float* __restrict__ whh1,
              const float* __restrict__ bih1, const float* __restrict__ bhh1,
              float* __restrict__ h0buf,       // [2][8][8][512] (sc), zeroed
              float* __restrict__ h1buf,       // [2][8][8][512] (sc), zeroed
              float* __restrict__ enc,         // [T][512][64] (cached)
              float* __restrict__ hTd, float* __restrict__ cTd, // [512][64]
              unsigned char* __restrict__ flags)  // [8][64], zeroed
{
  const int bid = blockIdx.x;
  const int g   = bid >> 6;          // batch group 0..7
  const int wgl = bid & 63;          // col-slice WG 0..63 (wgl%8 == bid%8)
  const int tid = threadIdx.x;

  __shared__ float in1[8][1028];     // [b][k]: k<512 h0[t-1], k>=512 h1[t-2]
  __shared__ float xs[8][76];        // x[t] slice
  __shared__ float gv[2][32][8];     // gate dots [layer][gate*8+j][b]

  const int b   = tid & 7;
  const int dL  = (tid >> 3) & 31;   // gate*8 + j
  const int lyr = tid >> 8;          // 0 or 1
  const int row = (dL >> 3) * HDIM + wgl * 8 + (dL & 7);

  const float* w_in;  const float* w_rec;  float bias;
  if (lyr == 0) {
    w_in = wih0 + (size_t)row * IDIM;  w_rec = whh0 + (size_t)row * HDIM;
    bias = bih0[row] + bhh0[row];
  } else {
    w_in = wih1 + (size_t)row * HDIM;  w_rec = whh1 + (size_t)row * HDIM;
    bias = bih1[row] + bhh1[row];
  }

  // cell-update role (tid<128)
  const int cL = tid >> 6, cj = (tid >> 3) & 7, cb = tid & 7;
  const int ccol = wgl * 8 + cj;
  float c_reg = 0.f;

  const unsigned* fw = (const unsigned*)(flags + g * 64);
  unsigned char* myflag = flags + g * 64 + wgl;

  for (int t = 0; t <= TT; ++t) {
    if (t > 0) {   // wait: all 64 group WGs finished step t-1
      if (tid < 64) {
        const unsigned tgt = (unsigned)(t & 255);
        for (;;) {
          int ok = 1;
          if (tid < 16) ok = bytes_ge(ldau(fw + tid), tgt);
          if (__all(ok)) break;
          __builtin_amdgcn_s_sleep(1);
        }
      }
      __syncthreads();
    }

    // ---- stage group h into LDS (coalesced 8B sc loads) + x (cached) ----
    {
      const float* s0 = h0buf + ((size_t)((t + 1) & 1) * 8 + g) * 4096; // h0[t-1]
      const float* s1 = h1buf + ((size_t)(t & 1) * 8 + g) * 4096;       // h1[t-2]
      const int off = tid * 8, sb = off >> 9, sk = off & 511;
      const double* p0 = (const double*)(s0 + off);
      const double* p1 = (const double*)(s1 + off);
      double a0 = lda8(p0), a1 = lda8(p0 + 1), a2 = lda8(p0 + 2), a3 = lda8(p0 + 3);
      double c0 = lda8(p1), c1 = lda8(p1 + 1), c2 = lda8(p1 + 2), c3 = lda8(p1 + 3);
      double* q0 = (double*)&in1[sb][sk];
      q0[0] = a0; q0[1] = a1; q0[2] = a2; q0[3] = a3;
      double* q1 = (double*)&in1[sb][512 + sk];
      q1[0] = c0; q1[1] = c1; q1[2] = c2; q1[3] = c3;
      if (t < TT) {
        const int xi_ = tid >> 3, xb = tid & 7;
        xs[xb][xi_] = xT[((size_t)t * IDIM + xi_) * BATCH + g * 8 + xb];
      }
    }
    __syncthreads();

    // ---- dot phase: one full-K dot per thread ---------------------------
    {
      const bool act = (lyr == 0) ? (t < TT) : (t >= 1);
      if (act) {
        float acc = 0.f;
        if (lyr == 0) {
#pragma unroll
          for (int k = 0; k < IDIM; k += 4) {
            float4 xv = *(const float4*)&xs[b][k];
            float4 wv = ld4(w_in + k);
            acc += xv.x * wv.x + xv.y * wv.y + xv.z * wv.z + xv.w * wv.w;
          }
#pragma unroll 4
          for (int k = 0; k < HDIM; k += 4) {
            float4 hv = *(const float4*)&in1[b][k];
            float4 wv = ld4(w_rec + k);
            acc += hv.x * wv.x + hv.y * wv.y + hv.z * wv.z + hv.w * wv.w;
          }
        } else {
#pragma unroll 4
          for (int k = 0; k < HDIM; k += 4) {
            float4 hv = *(const float4*)&in1[b][k];
            float4 wv = ld4(w_in + k);
            acc += hv.x * wv.x + hv.y * wv.y + hv.z * wv.z + hv.w * wv.w;
          }
#pragma unroll 4
          for (int k = 0; k < HDIM; k += 4) {
            float4 hv = *(const float4*)&in1[b][512 + k];
            float4 wv = ld4(w_rec + k);
            acc += hv.x * wv.x + hv.y * wv.y + hv.z * wv.z + hv.w * wv.w;
          }
        }
        gv[lyr][dL][b] = acc + bias;
      }
    }
    __syncthreads();

    // ---- cell update ----------------------------------------------------
    if (tid < 128) {
      const bool act = (cL == 0) ? (t < TT) : (t >= 1);
      if (act) {
        float gi = gv[cL][0 * 8 + cj][cb];
        float gf = gv[cL][1 * 8 + cj][cb];
        float gg = gv[cL][2 * 8 + cj][cb];
        float go = gv[cL][3 * 8 + cj][cb];
        float cn = sigm(gf) * c_reg + sigm(gi) * tanhf(gg);
        float hn = sigm(go) * tanhf(cn);
        c_reg = cn;
        if (cL == 0) {
          sta(h0buf + ((size_t)(t & 1) * 8 + g) * 4096 + cb * 512 + ccol, hn);
        } else {
          const int tau = t - 1;
          sta(h1buf + ((size_t)((t - 1) & 1) * 8 + g) * 4096 + cb * 512 + ccol, hn);
          enc[(size_t)tau * HB + ccol * BATCH + g * 8 + cb] = hn;
          if (tau == TT - 1) {
            hTd[ccol * BATCH + g * 8 + cb] = hn;
            cTd[ccol * BATCH + g * 8 + cb] = cn;
          }
        }
      }
    }
    __syncthreads();   // drain all waves' sc stores before publish
    if (t < TT && tid == 0) stab(myflag, (unsigned char)((t + 1) & 255));
  }
}

// ---------------------------------------------------------------------------
// Decoder LSTM cell (R8-proven): 2 h-cols {j0,j0+1}, all 64 b. 512 threads.
// ---------------------------------------------------------------------------
template <int DIN0>
__device__ __forceinline__ void cell_tile2(
    int j0, const float* __restrict__ in0,             // [DIN0][B]
    const float* __restrict__ h_in,                    // [512][B]
    const float* __restrict__ w_ih, const float* __restrict__ w_hh,
    const float* __restrict__ b_ih, const float* __restrict__ b_hh,
    float* __restrict__ c_state, float* __restrict__ h_out,  // [512][B]
    float* __restrict__ sm)
{
  const int tid = threadIdx.x;
  const int b  = tid & 63;
  const int ks = tid >> 6;
  constexpr int K  = DIN0 + HDIM;
  constexpr int KS = K / 8;
  const int k0 = ks * KS, k1 = k0 + KS;
  const int a0 = (k0 < DIN0) ? k0 : DIN0;
  const int a1 = (k1 < DIN0) ? k1 : DIN0;
  const int c0 = (k0 > DIN0) ? k0 - DIN0 : 0;
  const int c1 = (k1 > DIN0) ? k1 - DIN0 : 0;

  const float* wi = w_ih + (size_t)j0 * DIN0;
  const float* wh = w_hh + (size_t)j0 * HDIM;

  float acc[8] = {0.f, 0.f, 0.f, 0.f, 0.f, 0.f, 0.f, 0.f};
#pragma unroll 2
  for (int k = a0; k < a1; k += 4) {
    float x0 = in0[(k + 0) * BATCH + b], x1 = in0[(k + 1) * BATCH + b];
    float x2 = in0[(k + 2) * BATCH + b], x3 = in0[(k + 3) * BATCH + b];
#pragma unroll
    for (int d = 0; d < 8; ++d) {
      float4 w = ld4(wi + (size_t)((d >> 1) * HDIM + (d & 1)) * DIN0 + k);
      acc[d] += x0 * w.x + x1 * w.y + x2 * w.z + x3 * w.w;
    }
  }
#pragma unroll 2
  for (int k = c0; k < c1; k += 4) {
    float h0 = h_in[(k + 0) * BATCH + b], h1 = h_in[(k + 1) * BATCH + b];
    float h2 = h_in[(k + 2) * BATCH + b], h3 = h_in[(k + 3) * BATCH + b];
#pragma unroll
    for (int d = 0; d < 8; ++d) {
      float4 w = ld4(wh + (size_t)((d >> 1) * HDIM + (d & 1)) * HDIM + k);
      acc[d] += h0 * w.x + h1 * w.y + h2 * w.z + h3 * w.w;
    }
  }

  float* gl = sm + 8 * 64 * 9;
#pragma unroll
  for (int d = 0; d < 8; ++d) sm[(d * 64 + b) * 9 + ks] = acc[d];
  __syncthreads();
  {
    const int dd = tid >> 6, bb = tid & 63;
    float s = 0.f;
#pragma unroll
    for (int i = 0; i < 8; ++i) s += sm[(dd * 64 + bb) * 9 + i];
    const int r = (dd >> 1) * HDIM + j0 + (dd & 1);
    gl[dd * 64 + bb] = s + b_ih[r] + b_hh[r];
  }
  __syncthreads();
  if (tid < 128) {
    const int bb = tid & 63, cl = tid >> 6;
    const int jc = j0 + cl;
    float gi = gl[(0 + cl) * 64 + bb], gf = gl[(2 + cl) * 64 + bb];
    float gg = gl[(4 + cl) * 64 + bb], go = gl[(6 + cl) * 64 + bb];
    float cold = c_state[(size_t)jc * BATCH + bb];
    float cn = sigm(gf) * cold + sigm(gi) * tanhf(gg);
    float hn = sigm(go) * tanhf(cn);
    c_state[(size_t)jc * BATCH + bb] = cn;
    h_out[(size_t)jc * BATCH + bb] = hn;
  }
}

__global__ __launch_bounds__(512, 4)
void dec_gates(const float* __restrict__ xi, const float* __restrict__ h_cur,
               const float* __restrict__ w_ih, const float* __restrict__ w_hh,
               const float* __restrict__ b_ih, const float* __restrict__ b_hh,
               float* __restrict__ cst, float* __restrict__ h_out)
{
  __shared__ float sm[8 * 64 * 9 + 8 * 64];
  cell_tile2<HDIM>(blockIdx.x * 2, xi, h_cur, w_ih, w_hh, b_ih, b_hh,
                   cst, h_out, sm);
}

// ---------------------------------------------------------------------------
// scores[t][b] = dot(enc[t][.][b], h_cur[.][b]); WG handles 2 t's.
// ---------------------------------------------------------------------------
__global__ __launch_bounds__(512, 2)
void attn_scores(const float* __restrict__ enc,   // [T][H][B]
                 const float* __restrict__ h_cur, // [H][B]
                 float* __restrict__ scores)      // [T][B]
{
  __shared__ float red[2][8][64];
  const int tid = threadIdx.x;
  const int b  = tid & 63;
  const int ks = tid >> 6;
  const int t0 = blockIdx.x * 2;
  const float* e0 = enc + (size_t)t0 * HB + ks * 64 * BATCH;
  const float* e1 = e0 + HB;
  const float* hr = h_cur + ks * 64 * BATCH;
  float a0 = 0.f, a1 = 0.f;
#pragma unroll 4
  for (int k = 0; k < 64; ++k) {
    float hv = hr[k * BATCH + b];
    a0 += hv * e0[k * BATCH + b];
    a1 += hv * e1[k * BATCH + b];
  }
  red[0][ks][b] = a0;
  red[1][ks][b] = a1;
  __syncthreads();
  if (tid < 128) {
    int tl = tid >> 6;
    float s = 0.f;
#pragma unroll
    for (int i = 0; i < 8; ++i) s += red[tl][i][b];
    scores[(size_t)(t0 + tl) * BATCH + b] = s;
  }
}

// ---------------------------------------------------------------------------
// Per step s: per-WG softmax, ctx for 2 h-cols, pred_{s-1} (fc rows = same 2
// cols) -> out row s-1, xi = ctx + pred_{s-1}. s==0: dec_in = 0, no out write.
// ---------------------------------------------------------------------------
__global__ __launch_bounds__(512, 2)
void attn_ctx(const float* __restrict__ enc,     // [T][H][B]
              const float* __restrict__ scores,  // [T][B]
              const float* __restrict__ h_cur,   // [H][B]
              const float* __restrict__ w_fc, const float* __restrict__ b_fc,
              float* __restrict__ xi,            // [H][B]
              float* __restrict__ out,           // [B][24][C]
              int s)
{
  __shared__ float red[8][2][64];
  __shared__ float mz[2][64];
  __shared__ float ctxv[2][64];
  const int tid = threadIdx.x;
  const int b  = tid & 63;
  const int ts = tid >> 6;
  const int hc0 = blockIdx.x * 2;

  float m = -1e30f;
  for (int t = ts * 64; t < ts * 64 + 64; ++t)
    m = fmaxf(m, scores[(size_t)t * BATCH + b]);
  red[ts][0][b] = m;
  __syncthreads();
  if (tid < 64) {
    float mm = red[0][0][b];
#pragma unroll
    for (int i = 1; i < 8; ++i) mm = fmaxf(mm, red[i][0][b]);
    mz[0][b] = mm;
  }
  __syncthreads();
  m = mz[0][b];
  float z = 0.f;
  for (int t = ts * 64; t < ts * 64 + 64; ++t)
    z += expf(scores[(size_t)t * BATCH + b] - m);
  red[ts][1][b] = z;
  __syncthreads();
  if (tid < 64) {
    float zz = 0.f;
#pragma unroll
    for (int i = 0; i < 8; ++i) zz += red[i][1][b];
    mz[1][b] = 1.f / zz;
  }
  __syncthreads();
  const float rZ = mz[1][b];

  float a0 = 0.f, a1 = 0.f;
  const float* eb = enc + (size_t)hc0 * BATCH + b;
  for (int t = ts * 64; t < ts * 64 + 64; ++t) {
    float p = expf(scores[(size_t)t * BATCH + b] - m) * rZ;
    a0 += p * eb[(size_t)t * HB];
    a1 += p * eb[(size_t)t * HB + BATCH];
  }
  __syncthreads();
  red[ts][0][b] = a0;
  red[ts][1][b] = a1;
  __syncthreads();
  if (tid < 128) {
    int cl = tid >> 6;
    float c = 0.f;
#pragma unroll
    for (int i = 0; i < 8; ++i) c += red[i][cl][b];
    ctxv[cl][b] = c;
  }

  float p0 = 0.f, p1 = 0.f;
  if (s >= 1) {
    const float* w0 = w_fc + (size_t)hc0 * HDIM + ts * 64;
    const float* w1 = w0 + HDIM;
    const float* hr = h_cur + ts * 64 * BATCH;
#pragma unroll 2
    for (int k = 0; k < 64; k += 4) {
      float4 wa = ld4(w0 + k), wb = ld4(w1 + k);
      float h0 = hr[(k + 0) * BATCH + b], h1 = hr[(k + 1) * BATCH + b];
      float h2 = hr[(k + 2) * BATCH + b], h3 = hr[(k + 3) * BATCH + b];
      p0 += wa.x * h0 + wa.y * h1 + wa.z * h2 + wa.w * h3;
      p1 += wb.x * h0 + wb.y * h1 + wb.z * h2 + wb.w * h3;
    }
  }
  __syncthreads();
  red[ts][0][b] = p0;
  red[ts][1][b] = p1;
  __syncthreads();
  if (tid < 128) {
    int cl = tid >> 6;
    int cc = hc0 + cl;
    float pred = 0.f;
    if (s >= 1) {
#pragma unroll
      for (int i = 0; i < 8; ++i) pred += red[i][cl][b];
      pred += b_fc[cc];
      out[((size_t)b * NAHEAD + (s - 1)) * HDIM + cc] = pred;
    }
    xi[(size_t)cc * BATCH + b] = ctxv[cl][b] + pred;
  }
}

// ---------------------------------------------------------------------------
__global__ __launch_bounds__(512, 2)
void fc_out(const float* __restrict__ h, const float* __restrict__ w_fc,
            const float* __restrict__ b_fc, float* __restrict__ out, int srow)
{
  __shared__ float red[8][2][64];
  const int tid = threadIdx.x;
  const int b  = tid & 63;
  const int ks = tid >> 6;
  const int cc0 = blockIdx.x * 2;
  const float* w0 = w_fc + (size_t)cc0 * HDIM + ks * 64;
  const float* w1 = w0 + HDIM;
  const float* hr = h + ks * 64 * BATCH;
  float p0 = 0.f, p1 = 0.f;
#pragma unroll 2
  for (int k = 0; k < 64; k += 4) {
    float4 wa = ld4(w0 + k), wb = ld4(w1 + k);
    float h0 = hr[(k + 0) * BATCH + b], h1 = hr[(k + 1) * BATCH + b];
    float h2 = hr[(k + 2) * BATCH + b], h3 = hr[(k + 3) * BATCH + b];
    p0 += wa.x * h0 + wa.y * h1 + wa.z * h2 + wa.w * h3;
    p1 += wb.x * h0 + wb.y * h1 + wb.z * h2 + wb.w * h3;
  }
  red[ks][0][b] = p0;
  red[ks][1][b] = p1;
  __syncthreads();
  if (tid < 128) {
    int cl = tid >> 6;
    int cc = cc0 + cl;
    float p = 0.f;
#pragma unroll
    for (int i = 0; i < 8; ++i) p += red[i][cl][b];
    out[((size_t)b * NAHEAD + srow) * HDIM + cc] = p + b_fc[cc];
  }
}

// ---------------------------------------------------------------------------
// x [B][T][I] -> xT [T][I][B]
// ---------------------------------------------------------------------------
__global__ __launch_bounds__(256)
void transpose_x(const float* __restrict__ x, float* __restrict__ xT)
{
  __shared__ float tile[64][65];
  const int t = blockIdx.x;
  const int lane = threadIdx.x & 63;
  const int w    = threadIdx.x >> 6;
#pragma unroll
  for (int ii = 0; ii < 16; ++ii) {
    int b = w * 16 + ii;
    tile[b][lane] = x[((size_t)b * TT + t) * IDIM + lane];
  }
  __syncthreads();
#pragma unroll
  for (int ii = 0; ii < 16; ++ii) {
    int i = w * 16 + ii;
    xT[((size_t)t * IDIM + i) * BATCH + lane] = tile[lane][i];
  }
}

// ---------------------------------------------------------------------------
extern "C" void kernel_launch(void* const* d_in, const int* in_sizes, int n_in,
                              void* d_out, int out_size, void* d_ws, size_t ws_size,
                              hipStream_t stream) {
  const float* x     = (const float*)d_in[0];
  const float* w_ih0 = (const float*)d_in[1];
  const float* w_hh0 = (const float*)d_in[2];
  const float* b_ih0 = (const float*)d_in[3];
  const float* b_hh0 = (const float*)d_in[4];
  const float* w_ih1 = (const float*)d_in[5];
  const float* w_hh1 = (const float*)d_in[6];
  const float* b_ih1 = (const float*)d_in[7];
  const float* b_hh1 = (const float*)d_in[8];
  const float* w_ihd = (const float*)d_in[9];
  const float* w_hhd = (const float*)d_in[10];
  const float* b_ihd = (const float*)d_in[11];
  const float* b_hhd = (const float*)d_in[12];
  const float* w_fc  = (const float*)d_in[13];
  const float* b_fc  = (const float*)d_in[14];
  float* out = (float*)d_out;

  char* ws = (char*)d_ws;
  size_t off = 0;
  auto alloc = [&](size_t bytes) -> void* {
    void* p = ws + off;
    off += (bytes + 255) & ~(size_t)255;
    return p;
  };

  // ---- zero region (one memset) ----
  unsigned char* flags = (unsigned char*)alloc(8 * 64);
  float* h0buf = (float*)alloc(2 * 8 * 8 * 512 * 4);   // 256 KB
  float* h1buf = (float*)alloc(2 * 8 * 8 * 512 * 4);   // 256 KB
  const size_t zero_bytes = off;
  // ---- no-init scratch ----
  float* hTd  = (float*)alloc((size_t)HDIM * BATCH * 4);
  float* cTd  = (float*)alloc((size_t)HDIM * BATCH * 4);
  float* xT   = (float*)alloc((size_t)TT * IDIM * BATCH * 4);
  float* enc  = (float*)alloc((size_t)TT * HB * 4);
  float* scores = (float*)alloc((size_t)TT * BATCH * 4);
  float* xi     = (float*)alloc((size_t)HB * 4);
  float* hdec   = (float*)alloc((size_t)2 * HB * 4);
  (void)ws_size; (void)in_sizes; (void)n_in; (void)out_size;

  hipMemsetAsync(d_ws, 0, zero_bytes, stream);

  transpose_x<<<TT, 256, 0, stream>>>(x, xT);

  // entire 2-layer encoder: ONE persistent kernel, 512 group-barriers total
  lstm_enc<<<512, 512, 0, stream>>>(
      xT, w_ih0, w_hh0, b_ih0, b_hh0, w_ih1, w_hh1, b_ih1, b_hh1,
      h0buf, h1buf, enc, hTd, cTd, flags);

  // decoder: launch-based (proven), h starts at hTd, c continues in cTd
  const float* h_cur = hTd;
  for (int s = 0; s < NAHEAD; ++s) {
    attn_scores<<<256, 512, 0, stream>>>(enc, h_cur, scores);
    attn_ctx<<<256, 512, 0, stream>>>(enc, scores, h_cur, w_fc, b_fc,
                                      xi, out, s);
    float* h_nxt = hdec + (size_t)(s & 1) * HB;
    dec_gates<<<256, 512, 0, stream>>>(xi, h_cur, w_ihd, w_hhd,
                                       b_ihd, b_hhd, cTd, h_nxt);
    h_cur = h_nxt;
  }
  fc_out<<<256, 512, 0, stream>>>(h_cur, w_fc, b_fc, out, NAHEAD - 1);
}